// Round 1
// baseline (39241.391 us; speedup 1.0000x reference)
//
#include <hip/hip_runtime.h>
#include <hip/hip_bf16.h>
#include <hip/hip_cooperative_groups.h>

namespace cg = cooperative_groups;

typedef unsigned short ushort_t;
typedef unsigned int uint32;
typedef __attribute__((ext_vector_type(8))) __bf16 bf16x8;
typedef __attribute__((ext_vector_type(4))) float f32x4;
typedef __attribute__((ext_vector_type(4))) unsigned int u32x4;

#define SEQ_LEN 1024
#define DIN 512
#define DH  512
#define NBATCH 64
#define NWG 128
#define NTHR 256

#define XPACK_UNITS (SEQ_LEN * 16 * 64 * 4)        /* 4,194,304 16B units */
#define XPACK_BYTES ((size_t)XPACK_UNITS * 16)     /* 64 MiB */
#define WPACK_BYTES ((size_t)NWG * 32 * 64 * 16)   /* 4 MiB */

__device__ __forceinline__ ushort_t f2bf(float f) {
  unsigned u = __builtin_bit_cast(unsigned, f);
  unsigned r = (u + 0x7fffu + ((u >> 16) & 1u)) >> 16;
  return (ushort_t)r;
}

__device__ __forceinline__ float sigm(float x) {
  float e = __expf(-x);                      // safe: overflow -> inf -> rcp -> 0
  return __builtin_amdgcn_rcpf(1.f + e);
}
__device__ __forceinline__ float tanh_fast(float x) {
  float a = fabsf(x);
  float e = __expf(-2.f * a);                // in (0,1], never overflows
  float r = (1.f - e) * __builtin_amdgcn_rcpf(1.f + e);
  return copysignf(r, x);
}

// ---- phase 0: zero h double-buffer slot 0 (lives at start of d_out) ----
__global__ void zero_hbuf_kernel(u32x4* p) {
  int i = blockIdx.x * blockDim.x + threadIdx.x;   // 16*256 = 4096 units = 64KB
  u32x4 z = {0u, 0u, 0u, 0u};
  p[i] = z;
}

// ---- phase 0: pack x (f32 -> bf16, frag-major). unit (t,kk,b,hi) holds
// x[b][t][32kk+8hi+r], r=0..7. One 16B unit per thread. ----
__global__ void pack_x_kernel(const float* __restrict__ x, u32x4* __restrict__ xp) {
  unsigned u = blockIdx.x * blockDim.x + threadIdx.x;
  int hi = u & 3;
  int kk = (u >> 2) & 15;
  int t  = (u >> 6) & 1023;
  int b  = u >> 16;
  const float* src = x + (((size_t)b * SEQ_LEN + t) * DIN + (kk << 5) + (hi << 3));
  f32x4 f0 = *(const f32x4*)(src);
  f32x4 f1 = *(const f32x4*)(src + 4);
  u32x4 o;
  o[0] = f2bf(f0[0]) | ((uint32)f2bf(f0[1]) << 16);
  o[1] = f2bf(f0[2]) | ((uint32)f2bf(f0[3]) << 16);
  o[2] = f2bf(f1[0]) | ((uint32)f2bf(f1[1]) << 16);
  o[3] = f2bf(f1[2]) | ((uint32)f2bf(f1[3]) << 16);
  xp[(size_t)((t * 16 + kk) * 64 + b) * 4 + hi] = o;
}

// ---- phase 0: pack W_cat = [W_i; W_h] columns into per-WG frag-major slices.
// col = gate*512 + 4*wg + hcl ; p = 4*hcl + gate ; lane = 16*hi + p ;
// k = 32kk + 8hi + r. ----
__global__ void pack_w_kernel(const float* __restrict__ Wi, const float* __restrict__ Wh,
                              ushort_t* __restrict__ wp) {
  unsigned e = blockIdx.x * blockDim.x + threadIdx.x;  // 1024*2048 elements
  int k = e >> 11;
  int col = e & 2047;
  float v = (k < 512) ? Wi[(size_t)k * 2048 + col] : Wh[(size_t)(k - 512) * 2048 + col];
  int wg = (col & 511) >> 2;
  int hcl = col & 3;
  int gate = col >> 9;
  int p = (hcl << 2) | gate;
  int kk = k >> 5;
  int hi = (k >> 3) & 3;
  int r = k & 7;
  int lane = (hi << 4) | p;
  wp[((size_t)((wg * 32 + kk) * 64 + lane) << 3) + r] = f2bf(v);
}

// ---- persistent cooperative LSTM kernel ----
// gatesT tile per wave: D[16 gate-cols][16 batch] = Wp^T * X^T via 16x16x32 bf16 MFMA.
// D layout (HW-verified): col = lane&15 (batch), row = 4*(lane>>4)+reg (gate-col p).
// With p = 4*hcl+gate: each lane owns ONE h-column (hcl = lane>>4) and its 4 gates.
template<bool PACKED>
__global__ void __launch_bounds__(NTHR, 1)
lstm_coop(const float* __restrict__ x, const float* __restrict__ Wi,
          const float* __restrict__ Wh, const float* __restrict__ bias,
          const u32x4* __restrict__ xpack, const u32x4* __restrict__ wpack,
          ushort_t* hbuf, float* out)
{
  __shared__ u32x4 lA[2048];   // 32KB: frag-major weight slice [32 kk][64 lane]
  const int tid  = threadIdx.x;
  const int wg   = blockIdx.x;
  const int lane = tid & 63;
  const int wv   = tid >> 6;
  const int hi   = lane >> 4;
  const int lo   = lane & 15;
  const int b    = (wv << 4) | lo;

  if (PACKED) {
    const u32x4* wsrc = wpack + (size_t)wg * 2048;
    for (int i = tid; i < 2048; i += NTHR) lA[i] = wsrc[i];
  } else {
    for (int uu = tid; uu < 2048; uu += NTHR) {
      int kk = uu >> 6, ln = uu & 63, uhi = ln >> 4, p = ln & 15;
      int gate = p & 3, hcl = p >> 2;
      int col = gate * 512 + (wg << 2) + hcl;
      ushort_t tmp[8];
#pragma unroll
      for (int r = 0; r < 8; ++r) {
        int k = (kk << 5) + (uhi << 3) + r;
        float f = (k < 512) ? Wi[(size_t)k * 2048 + col] : Wh[(size_t)(k - 512) * 2048 + col];
        tmp[r] = f2bf(f);
      }
      u32x4 v;
      v[0] = tmp[0] | ((uint32)tmp[1] << 16);
      v[1] = tmp[2] | ((uint32)tmp[3] << 16);
      v[2] = tmp[4] | ((uint32)tmp[5] << 16);
      v[3] = tmp[6] | ((uint32)tmp[7] << 16);
      lA[uu] = v;
    }
  }
  __syncthreads();

  const float b0 = bias[0 * 512 + (wg << 2) + hi];
  const float b1 = bias[1 * 512 + (wg << 2) + hi];
  const float b2 = bias[2 * 512 + (wg << 2) + hi];
  const float b3 = bias[3 * 512 + (wg << 2) + hi];

  const int kh = (wg << 2) | hi;                       // this lane's h column
  const int hoff = (((kh >> 5) * 256 + b * 4 + ((kh >> 3) & 3)) << 3) + (kh & 7);

  float c = 0.f, hn = 0.f;
  cg::grid_group grid = cg::this_grid();

  for (int t = 0; t < SEQ_LEN; ++t) {
    bf16x8 xf[16];
    if (PACKED) {
      const u32x4* xb = xpack + (size_t)t * 4096 + b * 4 + hi;
#pragma unroll
      for (int kk = 0; kk < 16; ++kk) xf[kk] = __builtin_bit_cast(bf16x8, xb[kk * 256]);
    } else {
      const float* xr = x + ((size_t)b * SEQ_LEN + t) * DIN + (hi << 3);
#pragma unroll
      for (int kk = 0; kk < 16; ++kk) {
        f32x4 f0 = *(const f32x4*)(xr + (kk << 5));
        f32x4 f1 = *(const f32x4*)(xr + (kk << 5) + 4);
        u32x4 v;
        v[0] = f2bf(f0[0]) | ((uint32)f2bf(f0[1]) << 16);
        v[1] = f2bf(f0[2]) | ((uint32)f2bf(f0[3]) << 16);
        v[2] = f2bf(f1[0]) | ((uint32)f2bf(f1[1]) << 16);
        v[3] = f2bf(f1[2]) | ((uint32)f2bf(f1[3]) << 16);
        xf[kk] = __builtin_bit_cast(bf16x8, v);
      }
    }
    const u32x4* hr = (const u32x4*)hbuf + (size_t)(t & 1) * 4096 + b * 4 + hi;
    bf16x8 hf[16];
#pragma unroll
    for (int kk = 0; kk < 16; ++kk) hf[kk] = __builtin_bit_cast(bf16x8, hr[kk * 256]);

    f32x4 acc0 = {b0, b1, b2, b3};
    f32x4 acc1 = {0.f, 0.f, 0.f, 0.f};
#pragma unroll
    for (int kk = 0; kk < 16; ++kk) {
      bf16x8 a = __builtin_bit_cast(bf16x8, lA[kk * 64 + lane]);
      if (kk & 1) acc1 = __builtin_amdgcn_mfma_f32_16x16x32_bf16(a, xf[kk], acc1, 0, 0, 0);
      else        acc0 = __builtin_amdgcn_mfma_f32_16x16x32_bf16(a, xf[kk], acc0, 0, 0, 0);
    }
#pragma unroll
    for (int kk = 0; kk < 16; ++kk) {
      bf16x8 a = __builtin_bit_cast(bf16x8, lA[(16 + kk) * 64 + lane]);
      if (kk & 1) acc1 = __builtin_amdgcn_mfma_f32_16x16x32_bf16(a, hf[kk], acc1, 0, 0, 0);
      else        acc0 = __builtin_amdgcn_mfma_f32_16x16x32_bf16(a, hf[kk], acc0, 0, 0, 0);
    }
    const float gi = acc0[0] + acc1[0];
    const float gf = acc0[1] + acc1[1];
    const float gg = acc0[2] + acc1[2];
    const float go = acc0[3] + acc1[3];
    const float it = sigm(gi), ft = sigm(gf), ot = sigm(go);
    const float gt = tanh_fast(gg);
    c = ft * c + it * gt;
    hn = ot * tanh_fast(c);

    hbuf[(size_t)((t + 1) & 1) * 32768 + hoff] = f2bf(hn);
    __threadfence();      // release: make h stores agent-visible
    grid.sync();
    __threadfence();      // acquire: drop stale cached h lines
  }

  // final sync already happened at end of last iteration; safe to overwrite d_out
  out[(size_t)b * 512 + kh] = hn;
  out[32768 + (size_t)b * 512 + kh] = c;
}

extern "C" void kernel_launch(void* const* d_in, const int* in_sizes, int n_in,
                              void* d_out, int out_size, void* d_ws, size_t ws_size,
                              hipStream_t stream) {
  const float* x    = (const float*)d_in[0];
  const float* Wi   = (const float*)d_in[1];
  const float* Wh   = (const float*)d_in[2];
  const float* bias = (const float*)d_in[3];
  float* out = (float*)d_out;
  ushort_t* hbuf = (ushort_t*)d_out;   // h double-buffer scratch inside d_out (overwritten at end)

  zero_hbuf_kernel<<<16, 256, 0, stream>>>((u32x4*)d_out);

  bool packed = (d_ws != nullptr) && (ws_size >= XPACK_BYTES + WPACK_BYTES);
  const u32x4* xpack = (const u32x4*)d_ws;
  const u32x4* wpack = (const u32x4*)((char*)d_ws + XPACK_BYTES);

  if (packed) {
    pack_x_kernel<<<XPACK_UNITS / 256, 256, 0, stream>>>(x, (u32x4*)d_ws);
    pack_w_kernel<<<(1024 * 2048) / 256, 256, 0, stream>>>(Wi, Wh,
        (ushort_t*)((char*)d_ws + XPACK_BYTES));
  }

  void* args[] = {(void*)&x, (void*)&Wi, (void*)&Wh, (void*)&bias,
                  (void*)&xpack, (void*)&wpack, (void*)&hbuf, (void*)&out};
  if (packed) {
    void (*kfn)(const float*, const float*, const float*, const float*,
                const u32x4*, const u32x4*, ushort_t*, float*) = lstm_coop<true>;
    hipLaunchCooperativeKernel(reinterpret_cast<void*>(kfn), dim3(NWG), dim3(NTHR),
                               args, 0, stream);
  } else {
    void (*kfn)(const float*, const float*, const float*, const float*,
                const u32x4*, const u32x4*, ushort_t*, float*) = lstm_coop<false>;
    hipLaunchCooperativeKernel(reinterpret_cast<void*>(kfn), dim3(NWG), dim3(NTHR),
                               args, 0, stream);
  }
}

// Round 2
// 3699.268 us; speedup vs baseline: 10.6079x; 10.6079x over previous
//
#include <hip/hip_runtime.h>
#include <hip/hip_bf16.h>
#include <hip/hip_cooperative_groups.h>

namespace cg = cooperative_groups;

typedef unsigned short ushort_t;
typedef unsigned int uint32;
typedef __attribute__((ext_vector_type(8))) __bf16 bf16x8;
typedef __attribute__((ext_vector_type(4))) float f32x4;
typedef __attribute__((ext_vector_type(4))) unsigned int u32x4;

#define SEQ_LEN 1024
#define NWG 64
#define NTHR 256

#define XPACK_BYTES (64ull << 20)                  /* 1024*16*64*4 units * 16B */
#define WPACK_BYTES (4ull << 20)                   /* 64 WG * 64KB  */
#define HB_OFF  (XPACK_BYTES + WPACK_BYTES)        /* h double buffer, 128KB */
#define CNT_OFF (HB_OFF + (128ull << 10))          /* step counters, 64KB (64B stride) */
#define WS_NEED (CNT_OFF + (64ull << 10))

__device__ __forceinline__ ushort_t f2bf(float f) {
  unsigned u = __builtin_bit_cast(unsigned, f);
  unsigned r = (u + 0x7fffu + ((u >> 16) & 1u)) >> 16;
  return (ushort_t)r;
}
__device__ __forceinline__ float sigm(float x) {
  float e = __expf(-x);
  return __builtin_amdgcn_rcpf(1.f + e);
}
__device__ __forceinline__ float tanh_fast(float x) {
  float a = fabsf(x);
  float e = __expf(-2.f * a);
  float r = (1.f - e) * __builtin_amdgcn_rcpf(1.f + e);
  return copysignf(r, x);
}

__global__ void zero_mem_kernel(u32x4* p) {
  int i = blockIdx.x * blockDim.x + threadIdx.x;
  u32x4 z = {0u, 0u, 0u, 0u};
  p[i] = z;
}

// pack x (f32 -> bf16, frag-major): unit (t,kk,b,hi) holds x[b][t][32kk+8hi+r], r=0..7
__global__ void pack_x_kernel(const float* __restrict__ x, u32x4* __restrict__ xp) {
  unsigned u = blockIdx.x * blockDim.x + threadIdx.x;
  int hi = u & 3;
  int kk = (u >> 2) & 15;
  int t  = (u >> 6) & 1023;
  int b  = u >> 16;
  const float* src = x + (((size_t)b * SEQ_LEN + t) * 512 + (kk << 5) + (hi << 3));
  f32x4 f0 = *(const f32x4*)(src);
  f32x4 f1 = *(const f32x4*)(src + 4);
  u32x4 o;
  o[0] = f2bf(f0[0]) | ((uint32)f2bf(f0[1]) << 16);
  o[1] = f2bf(f0[2]) | ((uint32)f2bf(f0[3]) << 16);
  o[2] = f2bf(f1[0]) | ((uint32)f2bf(f1[1]) << 16);
  o[3] = f2bf(f1[2]) | ((uint32)f2bf(f1[3]) << 16);
  xp[(size_t)((t * 16 + kk) * 64 + b) * 4 + hi] = o;
}

// pack W = [W_i; W_h] per-WG frag-major: col = gate*512 + wg*8 + tau*4 + hcl,
// lane = 16*hi + (hcl<<2|gate), k = 32kk+8hi+r, dst [wg][kk(0..31)][tau][lane][r]
__global__ void pack_w_kernel(const float* __restrict__ Wi, const float* __restrict__ Wh,
                              ushort_t* __restrict__ wp) {
  unsigned e = blockIdx.x * blockDim.x + threadIdx.x;  // 1024*2048
  int k = e >> 11;
  int col = e & 2047;
  float v = (k < 512) ? Wi[(size_t)k * 2048 + col] : Wh[(size_t)(k - 512) * 2048 + col];
  int wg  = (col & 511) >> 3;
  int tau = (col >> 2) & 1;
  int hcl = col & 3;
  int gate = col >> 9;
  int p = (hcl << 2) | gate;
  int kk = k >> 5;
  int hi = (k >> 3) & 3;
  int r = k & 7;
  int lane = (hi << 4) | p;
  wp[(size_t)wg * 32768 + (size_t)(((kk * 2) + tau) * 64 + lane) * 8 + r] = f2bf(v);
}

// persistent LSTM. Per WG: 8 h-cols (2 MFMA tiles of 16 gate-cols each).
// D layout: col = lane&15 (batch), row = 4*(lane>>4)+reg = (hcl<<2|gate)
// => each lane owns h-cols kh0 = wg*8+(lane>>4), kh1 = kh0+4, gates = regs.
template<bool FAST>
__global__ void __launch_bounds__(NTHR, 1)
lstm_coop(const float* __restrict__ x, const float* __restrict__ Wi,
          const float* __restrict__ Wh, const float* __restrict__ bias,
          const u32x4* __restrict__ xpack, const u32x4* __restrict__ wpack,
          ushort_t* hbuf, uint32* cnt, float* out)
{
  __shared__ u32x4 lA[4096];   // 64KB: [kk 0..31][tau 0..1][lane 0..63] 16B frags
  const int tid  = threadIdx.x;
  const int wg   = blockIdx.x;
  const int lane = tid & 63;
  const int wv   = tid >> 6;
  const int hi2  = lane >> 4;
  const int lo   = lane & 15;
  const int b    = (wv << 4) | lo;

  if (FAST) {
    const u32x4* wsrc = wpack + (size_t)wg * 2048 * 2;   // 4096 units per WG
    for (int i = tid; i < 4096; i += NTHR) lA[i] = wsrc[i];
  } else {
    for (int uu = tid; uu < 4096; uu += NTHR) {
      int ln = uu & 63, tau = (uu >> 6) & 1, kk = uu >> 7;
      int uhi = ln >> 4, p = ln & 15;
      int gate = p & 3, hcl = p >> 2;
      int col = gate * 512 + (wg << 3) + tau * 4 + hcl;
      ushort_t tmp[8];
#pragma unroll
      for (int r = 0; r < 8; ++r) {
        int k = (kk << 5) + (uhi << 3) + r;
        float f = (k < 512) ? Wi[(size_t)k * 2048 + col] : Wh[(size_t)(k - 512) * 2048 + col];
        tmp[r] = f2bf(f);
      }
      u32x4 v;
      v[0] = tmp[0] | ((uint32)tmp[1] << 16);
      v[1] = tmp[2] | ((uint32)tmp[3] << 16);
      v[2] = tmp[4] | ((uint32)tmp[5] << 16);
      v[3] = tmp[6] | ((uint32)tmp[7] << 16);
      lA[uu] = v;
    }
  }
  __syncthreads();

  const int kh0 = (wg << 3) | hi2;
  const int kh1 = kh0 + 4;
  const float b00 = bias[0 * 512 + kh0], b01 = bias[1 * 512 + kh0];
  const float b02 = bias[2 * 512 + kh0], b03 = bias[3 * 512 + kh0];
  const float b10 = bias[0 * 512 + kh1], b11 = bias[1 * 512 + kh1];
  const float b12 = bias[2 * 512 + kh1], b13 = bias[3 * 512 + kh1];

  const int hoff0 = (((kh0 >> 5) * 256 + b * 4 + ((kh0 >> 3) & 3)) << 3) + (kh0 & 7);
  const int hoff1 = hoff0 + 4;

  // hoist recurrent-weight fragments into registers (loop-invariant, 128 VGPRs)
  bf16x8 whA[16], whB[16];
#pragma unroll
  for (int kk = 0; kk < 16; ++kk) {
    whA[kk] = __builtin_bit_cast(bf16x8, lA[((16 + kk) * 2 + 0) * 64 + lane]);
    whB[kk] = __builtin_bit_cast(bf16x8, lA[((16 + kk) * 2 + 1) * 64 + lane]);
  }

  float c0 = 0.f, c1 = 0.f, hn0 = 0.f, hn1 = 0.f;
  cg::grid_group grid = cg::this_grid();

  for (int t = 0; t < SEQ_LEN; ++t) {
    // ---- x-projection part (independent of h; hides under the barrier wait) ----
    f32x4 ax0 = {b00, b01, b02, b03};
    f32x4 ax1 = {b10, b11, b12, b13};
    if (FAST) {
      const u32x4* xb = xpack + (size_t)t * 4096 + b * 4 + hi2;
#pragma unroll
      for (int kk = 0; kk < 16; ++kk) {
        bf16x8 xv = __builtin_bit_cast(bf16x8, xb[kk * 256]);
        bf16x8 a0 = __builtin_bit_cast(bf16x8, lA[(kk * 2 + 0) * 64 + lane]);
        bf16x8 a1 = __builtin_bit_cast(bf16x8, lA[(kk * 2 + 1) * 64 + lane]);
        ax0 = __builtin_amdgcn_mfma_f32_16x16x32_bf16(a0, xv, ax0, 0, 0, 0);
        ax1 = __builtin_amdgcn_mfma_f32_16x16x32_bf16(a1, xv, ax1, 0, 0, 0);
      }
    } else {
      const float* xr = x + ((size_t)b * SEQ_LEN + t) * 512 + (hi2 << 3);
#pragma unroll
      for (int kk = 0; kk < 16; ++kk) {
        f32x4 f0 = *(const f32x4*)(xr + (kk << 5));
        f32x4 f1 = *(const f32x4*)(xr + (kk << 5) + 4);
        u32x4 v;
        v[0] = f2bf(f0[0]) | ((uint32)f2bf(f0[1]) << 16);
        v[1] = f2bf(f0[2]) | ((uint32)f2bf(f0[3]) << 16);
        v[2] = f2bf(f1[0]) | ((uint32)f2bf(f1[1]) << 16);
        v[3] = f2bf(f1[2]) | ((uint32)f2bf(f1[3]) << 16);
        bf16x8 xv = __builtin_bit_cast(bf16x8, v);
        bf16x8 a0 = __builtin_bit_cast(bf16x8, lA[(kk * 2 + 0) * 64 + lane]);
        bf16x8 a1 = __builtin_bit_cast(bf16x8, lA[(kk * 2 + 1) * 64 + lane]);
        ax0 = __builtin_amdgcn_mfma_f32_16x16x32_bf16(a0, xv, ax0, 0, 0, 0);
        ax1 = __builtin_amdgcn_mfma_f32_16x16x32_bf16(a1, xv, ax1, 0, 0, 0);
      }
    }

    // ---- wait for h_t (flag barrier; no cache-maintenance fences) ----
    if (FAST) {
      if (t > 0) {
        if (tid == 0) {
          const uint32* ca = cnt + (size_t)(t - 1) * 16;  // 64B stride
          uint32 v;
          while (true) {
            asm volatile("global_load_dword %0, %1, off sc0 sc1\n\ts_waitcnt vmcnt(0)"
                         : "=v"(v) : "v"(ca) : "memory");
            if (v >= (uint32)NWG) break;
            asm volatile("s_sleep 1" ::: "memory");
          }
        }
        __syncthreads();
      }
    }

    // ---- load h_t fragments (coherence-point loads on FAST path) ----
    const u32x4* hr = (const u32x4*)hbuf + (size_t)(t & 1) * 4096 + b * 4 + hi2;
    u32x4 hreg[16];
    if (FAST) {
#pragma unroll
      for (int kk = 0; kk < 16; ++kk)
        asm volatile("global_load_dwordx4 %0, %1, off sc0 sc1"
                     : "=v"(hreg[kk]) : "v"(hr + kk * 256) : "memory");
      asm volatile("s_waitcnt vmcnt(0)" ::: "memory");
      __builtin_amdgcn_sched_barrier(0);
    } else {
#pragma unroll
      for (int kk = 0; kk < 16; ++kk) hreg[kk] = hr[kk * 256];
    }

    // ---- recurrent part ----
    f32x4 ah0 = {0.f, 0.f, 0.f, 0.f};
    f32x4 ah1 = {0.f, 0.f, 0.f, 0.f};
#pragma unroll
    for (int kk = 0; kk < 16; ++kk) {
      bf16x8 hv = __builtin_bit_cast(bf16x8, hreg[kk]);
      ah0 = __builtin_amdgcn_mfma_f32_16x16x32_bf16(whA[kk], hv, ah0, 0, 0, 0);
      ah1 = __builtin_amdgcn_mfma_f32_16x16x32_bf16(whB[kk], hv, ah1, 0, 0, 0);
    }

    // ---- cell update (2 cells per lane) ----
    {
      float gi = ax0[0] + ah0[0], gf = ax0[1] + ah0[1];
      float gg = ax0[2] + ah0[2], go = ax0[3] + ah0[3];
      float it = sigm(gi), ft = sigm(gf), ot = sigm(go), gt = tanh_fast(gg);
      c0 = ft * c0 + it * gt;
      hn0 = ot * tanh_fast(c0);
    }
    {
      float gi = ax1[0] + ah1[0], gf = ax1[1] + ah1[1];
      float gg = ax1[2] + ah1[2], go = ax1[3] + ah1[3];
      float it = sigm(gi), ft = sigm(gf), ot = sigm(go), gt = tanh_fast(gg);
      c1 = ft * c1 + it * gt;
      hn1 = ot * tanh_fast(c1);
    }

    if (t < SEQ_LEN - 1) {
      ushort_t* hw = hbuf + (size_t)((t + 1) & 1) * 32768;
      if (FAST) {
        uint32 v0 = f2bf(hn0), v1 = f2bf(hn1);
        asm volatile("global_store_short %0, %1, off sc0 sc1"
                     :: "v"(hw + hoff0), "v"(v0) : "memory");
        asm volatile("global_store_short %0, %1, off sc0 sc1"
                     :: "v"(hw + hoff1), "v"(v1) : "memory");
        asm volatile("s_waitcnt vmcnt(0)" ::: "memory");
        __syncthreads();                 // whole WG's stores drained
        if (tid == 0) {
          uint32* ca = cnt + (size_t)t * 16;
          uint32 one = 1;
          asm volatile("global_atomic_add %0, %1, off sc1"
                       :: "v"(ca), "v"(one) : "memory");
        }
      } else {
        hw[hoff0] = f2bf(hn0);
        hw[hoff1] = f2bf(hn1);
        __threadfence();
        grid.sync();
        __threadfence();
      }
    } else if (!FAST) {
      __threadfence();
      grid.sync();   // d_out aliases hbuf in slow path: sync before final writes
    }
  }

  out[(size_t)b * 512 + kh0] = hn0;
  out[(size_t)b * 512 + kh1] = hn1;
  out[32768 + (size_t)b * 512 + kh0] = c0;
  out[32768 + (size_t)b * 512 + kh1] = c1;
}

extern "C" void kernel_launch(void* const* d_in, const int* in_sizes, int n_in,
                              void* d_out, int out_size, void* d_ws, size_t ws_size,
                              hipStream_t stream) {
  const float* x    = (const float*)d_in[0];
  const float* Wi   = (const float*)d_in[1];
  const float* Wh   = (const float*)d_in[2];
  const float* bias = (const float*)d_in[3];
  float* out = (float*)d_out;

  bool fast = (d_ws != nullptr) && (ws_size >= WS_NEED);

  if (fast) {
    const u32x4* xpack = (const u32x4*)d_ws;
    const u32x4* wpack = (const u32x4*)((char*)d_ws + XPACK_BYTES);
    ushort_t* hbuf = (ushort_t*)((char*)d_ws + HB_OFF);
    uint32* cnt = (uint32*)((char*)d_ws + CNT_OFF);

    zero_mem_kernel<<<48, 256, 0, stream>>>((u32x4*)((char*)d_ws + HB_OFF)); // 192KB
    pack_x_kernel<<<16384, 256, 0, stream>>>(x, (u32x4*)d_ws);
    pack_w_kernel<<<8192, 256, 0, stream>>>(Wi, Wh, (ushort_t*)((char*)d_ws + XPACK_BYTES));

    void* args[] = {(void*)&x, (void*)&Wi, (void*)&Wh, (void*)&bias,
                    (void*)&xpack, (void*)&wpack, (void*)&hbuf, (void*)&cnt, (void*)&out};
    void (*kfn)(const float*, const float*, const float*, const float*,
                const u32x4*, const u32x4*, ushort_t*, uint32*, float*) = lstm_coop<true>;
    hipLaunchCooperativeKernel(reinterpret_cast<void*>(kfn), dim3(NWG), dim3(NTHR),
                               args, 0, stream);
  } else {
    ushort_t* hbuf = (ushort_t*)d_out;
    uint32* cnt = (uint32*)d_out;  // unused on slow path
    const u32x4* xpack = (const u32x4*)x;
    const u32x4* wpack = (const u32x4*)Wi;

    zero_mem_kernel<<<16, 256, 0, stream>>>((u32x4*)d_out);  // 64KB slot0

    void* args[] = {(void*)&x, (void*)&Wi, (void*)&Wh, (void*)&bias,
                    (void*)&xpack, (void*)&wpack, (void*)&hbuf, (void*)&cnt, (void*)&out};
    void (*kfn)(const float*, const float*, const float*, const float*,
                const u32x4*, const u32x4*, ushort_t*, uint32*, float*) = lstm_coop<false>;
    hipLaunchCooperativeKernel(reinterpret_cast<void*>(kfn), dim3(NWG), dim3(NTHR),
                               args, 0, stream);
  }
}

// Round 3
// 3230.530 us; speedup vs baseline: 12.1470x; 1.1451x over previous
//
#include <hip/hip_runtime.h>
#include <hip/hip_bf16.h>
#include <hip/hip_cooperative_groups.h>

namespace cg = cooperative_groups;

typedef unsigned short ushort_t;
typedef unsigned int uint32;
typedef __attribute__((ext_vector_type(8))) __bf16 bf16x8;
typedef __attribute__((ext_vector_type(4))) float f32x4;
typedef __attribute__((ext_vector_type(4))) unsigned int u32x4;

#define SEQ_LEN 1024
#define NWG 64
#define NTHR 256

#define XPACK_BYTES (64ull << 20)                  /* 1024*16*64*4 units * 16B */
#define WPACK_BYTES (4ull << 20)                   /* 64 WG * 64KB  */
#define HB_OFF  (XPACK_BYTES + WPACK_BYTES)        /* h double buffer, 128KB */
#define CNT_OFF (HB_OFF + (128ull << 10))          /* per-wave flags, 1KB used */
#define WS_NEED (CNT_OFF + (64ull << 10))

__device__ __forceinline__ ushort_t f2bf(float f) {
  unsigned u = __builtin_bit_cast(unsigned, f);
  unsigned r = (u + 0x7fffu + ((u >> 16) & 1u)) >> 16;
  return (ushort_t)r;
}
__device__ __forceinline__ float sigm(float x) {
  float e = __expf(-x);
  return __builtin_amdgcn_rcpf(1.f + e);
}
__device__ __forceinline__ float tanh_fast(float x) {
  float a = fabsf(x);
  float e = __expf(-2.f * a);
  float r = (1.f - e) * __builtin_amdgcn_rcpf(1.f + e);
  return copysignf(r, x);
}

__global__ void zero_mem_kernel(u32x4* p) {
  int i = blockIdx.x * blockDim.x + threadIdx.x;
  u32x4 z = {0u, 0u, 0u, 0u};
  p[i] = z;
}

// pack x (f32 -> bf16, frag-major): unit (t,kk,b,hi) holds x[b][t][32kk+8hi+r], r=0..7
__global__ void pack_x_kernel(const float* __restrict__ x, u32x4* __restrict__ xp) {
  unsigned u = blockIdx.x * blockDim.x + threadIdx.x;
  int hi = u & 3;
  int kk = (u >> 2) & 15;
  int t  = (u >> 6) & 1023;
  int b  = u >> 16;
  const float* src = x + (((size_t)b * SEQ_LEN + t) * 512 + (kk << 5) + (hi << 3));
  f32x4 f0 = *(const f32x4*)(src);
  f32x4 f1 = *(const f32x4*)(src + 4);
  u32x4 o;
  o[0] = f2bf(f0[0]) | ((uint32)f2bf(f0[1]) << 16);
  o[1] = f2bf(f0[2]) | ((uint32)f2bf(f0[3]) << 16);
  o[2] = f2bf(f1[0]) | ((uint32)f2bf(f1[1]) << 16);
  o[3] = f2bf(f1[2]) | ((uint32)f2bf(f1[3]) << 16);
  xp[(size_t)((t * 16 + kk) * 64 + b) * 4 + hi] = o;
}

// pack W = [W_i; W_h] per-WG frag-major: col = gate*512 + wg*8 + tau*4 + hcl,
// lane = 16*hi + (hcl<<2|gate), k = 32kk+8hi+r, dst [wg][kk(0..31)][tau][lane][r]
__global__ void pack_w_kernel(const float* __restrict__ Wi, const float* __restrict__ Wh,
                              ushort_t* __restrict__ wp) {
  unsigned e = blockIdx.x * blockDim.x + threadIdx.x;  // 1024*2048
  int k = e >> 11;
  int col = e & 2047;
  float v = (k < 512) ? Wi[(size_t)k * 2048 + col] : Wh[(size_t)(k - 512) * 2048 + col];
  int wg  = (col & 511) >> 3;
  int tau = (col >> 2) & 1;
  int hcl = col & 3;
  int gate = col >> 9;
  int p = (hcl << 2) | gate;
  int kk = k >> 5;
  int hi = (k >> 3) & 3;
  int r = k & 7;
  int lane = (hi << 4) | p;
  wp[(size_t)wg * 32768 + (size_t)(((kk * 2) + tau) * 64 + lane) * 8 + r] = f2bf(v);
}

// persistent LSTM. Per WG: 8 h-cols (2 MFMA tiles of 16 gate-cols each).
// D layout: col = lane&15 (batch), row = 4*(lane>>4)+reg = (hcl<<2|gate)
// => each lane owns h-cols kh0 = wg*8+(lane>>4), kh1 = kh0+4, gates = regs.
// Sync: 256 monotonic per-wave flags (u32x4 per WG). No atomics, no syncthreads,
// no sleep. Flag[wg][wv] = number of h-steps that wave has published.
template<bool FAST>
__global__ void __launch_bounds__(NTHR, 1)
lstm_coop(const float* __restrict__ x, const float* __restrict__ Wi,
          const float* __restrict__ Wh, const float* __restrict__ bias,
          const u32x4* __restrict__ xpack, const u32x4* __restrict__ wpack,
          ushort_t* hbuf, uint32* flags, float* out)
{
  __shared__ u32x4 lA[4096];   // 64KB: [kk 0..31][tau 0..1][lane 0..63] 16B frags
  const int tid  = threadIdx.x;
  const int wg   = blockIdx.x;
  const int lane = tid & 63;
  const int wv   = tid >> 6;
  const int hi2  = lane >> 4;
  const int lo   = lane & 15;
  const int b    = (wv << 4) | lo;

  if (FAST) {
    const u32x4* wsrc = wpack + (size_t)wg * 2048 * 2;   // 4096 units per WG
    for (int i = tid; i < 4096; i += NTHR) lA[i] = wsrc[i];
  } else {
    for (int uu = tid; uu < 4096; uu += NTHR) {
      int ln = uu & 63, tau = (uu >> 6) & 1, kk = uu >> 7;
      int uhi = ln >> 4, p = ln & 15;
      int gate = p & 3, hcl = p >> 2;
      int col = gate * 512 + (wg << 3) + tau * 4 + hcl;
      ushort_t tmp[8];
#pragma unroll
      for (int r = 0; r < 8; ++r) {
        int k = (kk << 5) + (uhi << 3) + r;
        float f = (k < 512) ? Wi[(size_t)k * 2048 + col] : Wh[(size_t)(k - 512) * 2048 + col];
        tmp[r] = f2bf(f);
      }
      u32x4 v;
      v[0] = tmp[0] | ((uint32)tmp[1] << 16);
      v[1] = tmp[2] | ((uint32)tmp[3] << 16);
      v[2] = tmp[4] | ((uint32)tmp[5] << 16);
      v[3] = tmp[6] | ((uint32)tmp[7] << 16);
      lA[uu] = v;
    }
  }
  __syncthreads();

  const int kh0 = (wg << 3) | hi2;
  const int kh1 = kh0 + 4;
  const float b00 = bias[0 * 512 + kh0], b01 = bias[1 * 512 + kh0];
  const float b02 = bias[2 * 512 + kh0], b03 = bias[3 * 512 + kh0];
  const float b10 = bias[0 * 512 + kh1], b11 = bias[1 * 512 + kh1];
  const float b12 = bias[2 * 512 + kh1], b13 = bias[3 * 512 + kh1];

  const int hoff0 = (((kh0 >> 5) * 256 + b * 4 + ((kh0 >> 3) & 3)) << 3) + (kh0 & 7);
  const int hoff1 = hoff0 + 4;

  // recurrent-weight fragments (compiler may keep in regs or re-read LDS)
  bf16x8 whA[16], whB[16];
#pragma unroll
  for (int kk = 0; kk < 16; ++kk) {
    whA[kk] = __builtin_bit_cast(bf16x8, lA[((16 + kk) * 2 + 0) * 64 + lane]);
    whB[kk] = __builtin_bit_cast(bf16x8, lA[((16 + kk) * 2 + 1) * 64 + lane]);
  }

  float c0 = 0.f, c1 = 0.f, hn0 = 0.f, hn1 = 0.f;
  cg::grid_group grid = cg::this_grid();

  for (int t = 0; t < SEQ_LEN; ++t) {
    // ---- x-projection part (independent of h; runs while producers finish) ----
    f32x4 ax0 = {b00, b01, b02, b03};
    f32x4 ax1 = {b10, b11, b12, b13};
    if (FAST) {
      const u32x4* xb = xpack + (size_t)t * 4096 + b * 4 + hi2;
#pragma unroll
      for (int kk = 0; kk < 16; ++kk) {
        bf16x8 xv = __builtin_bit_cast(bf16x8, xb[kk * 256]);
        bf16x8 a0 = __builtin_bit_cast(bf16x8, lA[(kk * 2 + 0) * 64 + lane]);
        bf16x8 a1 = __builtin_bit_cast(bf16x8, lA[(kk * 2 + 1) * 64 + lane]);
        ax0 = __builtin_amdgcn_mfma_f32_16x16x32_bf16(a0, xv, ax0, 0, 0, 0);
        ax1 = __builtin_amdgcn_mfma_f32_16x16x32_bf16(a1, xv, ax1, 0, 0, 0);
      }
    } else {
      const float* xr = x + ((size_t)b * SEQ_LEN + t) * 512 + (hi2 << 3);
#pragma unroll
      for (int kk = 0; kk < 16; ++kk) {
        f32x4 f0 = *(const f32x4*)(xr + (kk << 5));
        f32x4 f1 = *(const f32x4*)(xr + (kk << 5) + 4);
        u32x4 v;
        v[0] = f2bf(f0[0]) | ((uint32)f2bf(f0[1]) << 16);
        v[1] = f2bf(f0[2]) | ((uint32)f2bf(f0[3]) << 16);
        v[2] = f2bf(f1[0]) | ((uint32)f2bf(f1[1]) << 16);
        v[3] = f2bf(f1[2]) | ((uint32)f2bf(f1[3]) << 16);
        bf16x8 xv = __builtin_bit_cast(bf16x8, v);
        bf16x8 a0 = __builtin_bit_cast(bf16x8, lA[(kk * 2 + 0) * 64 + lane]);
        bf16x8 a1 = __builtin_bit_cast(bf16x8, lA[(kk * 2 + 1) * 64 + lane]);
        ax0 = __builtin_amdgcn_mfma_f32_16x16x32_bf16(a0, xv, ax0, 0, 0, 0);
        ax1 = __builtin_amdgcn_mfma_f32_16x16x32_bf16(a1, xv, ax1, 0, 0, 0);
      }
    }

    // ---- wait for h_t: each wave independently polls all 256 wave-flags ----
    if (FAST) {
      if (t > 0) {
        const u32x4* fa = (const u32x4*)flags + lane;   // lane L -> WG L's 4 flags
        const uint32 tt = (uint32)t;
        while (true) {
          u32x4 v;
          asm volatile("global_load_dwordx4 %0, %1, off sc0 sc1\n\ts_waitcnt vmcnt(0)"
                       : "=v"(v) : "v"(fa) : "memory");
          bool ok = (v[0] >= tt) & (v[1] >= tt) & (v[2] >= tt) & (v[3] >= tt);
          if (__all(ok)) break;
        }
      }
    }

    // ---- load h_t fragments (coherence-point loads on FAST path) ----
    const u32x4* hr = (const u32x4*)hbuf + (size_t)(t & 1) * 4096 + b * 4 + hi2;
    u32x4 hreg[16];
    if (FAST) {
#pragma unroll
      for (int kk = 0; kk < 16; ++kk)
        asm volatile("global_load_dwordx4 %0, %1, off sc0 sc1"
                     : "=v"(hreg[kk]) : "v"(hr + kk * 256) : "memory");
      asm volatile("s_waitcnt vmcnt(0)" ::: "memory");
      __builtin_amdgcn_sched_barrier(0);
    } else {
#pragma unroll
      for (int kk = 0; kk < 16; ++kk) hreg[kk] = hr[kk * 256];
    }

    // ---- recurrent part ----
    f32x4 ah0 = {0.f, 0.f, 0.f, 0.f};
    f32x4 ah1 = {0.f, 0.f, 0.f, 0.f};
#pragma unroll
    for (int kk = 0; kk < 16; ++kk) {
      bf16x8 hv = __builtin_bit_cast(bf16x8, hreg[kk]);
      ah0 = __builtin_amdgcn_mfma_f32_16x16x32_bf16(whA[kk], hv, ah0, 0, 0, 0);
      ah1 = __builtin_amdgcn_mfma_f32_16x16x32_bf16(whB[kk], hv, ah1, 0, 0, 0);
    }

    // ---- cell update (2 cells per lane) ----
    {
      float gi = ax0[0] + ah0[0], gf = ax0[1] + ah0[1];
      float gg = ax0[2] + ah0[2], go = ax0[3] + ah0[3];
      float it = sigm(gi), ft = sigm(gf), ot = sigm(go), gt = tanh_fast(gg);
      c0 = ft * c0 + it * gt;
      hn0 = ot * tanh_fast(c0);
    }
    {
      float gi = ax1[0] + ah1[0], gf = ax1[1] + ah1[1];
      float gg = ax1[2] + ah1[2], go = ax1[3] + ah1[3];
      float it = sigm(gi), ft = sigm(gf), ot = sigm(go), gt = tanh_fast(gg);
      c1 = ft * c1 + it * gt;
      hn1 = ot * tanh_fast(c1);
    }

    if (t < SEQ_LEN - 1) {
      ushort_t* hw = hbuf + (size_t)((t + 1) & 1) * 32768;
      if (FAST) {
        uint32 v0 = f2bf(hn0), v1 = f2bf(hn1);
        asm volatile("global_store_short %0, %1, off sc0 sc1"
                     :: "v"(hw + hoff0), "v"(v0) : "memory");
        asm volatile("global_store_short %0, %1, off sc0 sc1"
                     :: "v"(hw + hoff1), "v"(v1) : "memory");
        asm volatile("s_waitcnt vmcnt(0)" ::: "memory");
        __builtin_amdgcn_sched_barrier(0);
        if (lane == 0) {                       // per-wave flag, plain store (no RMW)
          uint32* fp = flags + (wg << 2) + wv;
          uint32 val = (uint32)(t + 1);
          asm volatile("global_store_dword %0, %1, off sc0 sc1"
                       :: "v"(fp), "v"(val) : "memory");
        }
      } else {
        hw[hoff0] = f2bf(hn0);
        hw[hoff1] = f2bf(hn1);
        __threadfence();
        grid.sync();
        __threadfence();
      }
    } else if (!FAST) {
      __threadfence();
      grid.sync();   // d_out aliases hbuf in slow path: sync before final writes
    }
  }

  out[(size_t)b * 512 + kh0] = hn0;
  out[(size_t)b * 512 + kh1] = hn1;
  out[32768 + (size_t)b * 512 + kh0] = c0;
  out[32768 + (size_t)b * 512 + kh1] = c1;
}

extern "C" void kernel_launch(void* const* d_in, const int* in_sizes, int n_in,
                              void* d_out, int out_size, void* d_ws, size_t ws_size,
                              hipStream_t stream) {
  const float* x    = (const float*)d_in[0];
  const float* Wi   = (const float*)d_in[1];
  const float* Wh   = (const float*)d_in[2];
  const float* bias = (const float*)d_in[3];
  float* out = (float*)d_out;

  bool fast = (d_ws != nullptr) && (ws_size >= WS_NEED);

  if (fast) {
    const u32x4* xpack = (const u32x4*)d_ws;
    const u32x4* wpack = (const u32x4*)((char*)d_ws + XPACK_BYTES);
    ushort_t* hbuf = (ushort_t*)((char*)d_ws + HB_OFF);
    uint32* flags = (uint32*)((char*)d_ws + CNT_OFF);

    zero_mem_kernel<<<48, 256, 0, stream>>>((u32x4*)((char*)d_ws + HB_OFF)); // 192KB: hbuf+flags
    pack_x_kernel<<<16384, 256, 0, stream>>>(x, (u32x4*)d_ws);
    pack_w_kernel<<<8192, 256, 0, stream>>>(Wi, Wh, (ushort_t*)((char*)d_ws + XPACK_BYTES));

    void* args[] = {(void*)&x, (void*)&Wi, (void*)&Wh, (void*)&bias,
                    (void*)&xpack, (void*)&wpack, (void*)&hbuf, (void*)&flags, (void*)&out};
    void (*kfn)(const float*, const float*, const float*, const float*,
                const u32x4*, const u32x4*, ushort_t*, uint32*, float*) = lstm_coop<true>;
    hipLaunchCooperativeKernel(reinterpret_cast<void*>(kfn), dim3(NWG), dim3(NTHR),
                               args, 0, stream);
  } else {
    ushort_t* hbuf = (ushort_t*)d_out;
    uint32* flags = (uint32*)d_out;  // unused on slow path
    const u32x4* xpack = (const u32x4*)x;
    const u32x4* wpack = (const u32x4*)Wi;

    zero_mem_kernel<<<16, 256, 0, stream>>>((u32x4*)d_out);  // 64KB slot0

    void* args[] = {(void*)&x, (void*)&Wi, (void*)&Wh, (void*)&bias,
                    (void*)&xpack, (void*)&wpack, (void*)&hbuf, (void*)&flags, (void*)&out};
    void (*kfn)(const float*, const float*, const float*, const float*,
                const u32x4*, const u32x4*, ushort_t*, uint32*, float*) = lstm_coop<false>;
    hipLaunchCooperativeKernel(reinterpret_cast<void*>(kfn), dim3(NWG), dim3(NTHR),
                               args, 0, stream);
  }
}